// Round 9
// baseline (55.642 us; speedup 1.0000x reference)
//
#include <hip/hip_runtime.h>

namespace {
constexpr int H = 512;
constexpr int W = 512;
constexpr int NC = 96;                   // 32 images * 3 channels (independent planes)
constexpr int RSTRIP = 32;               // output rows per block
constexpr int SPP = H / RSTRIP;          // 16 strips per plane
constexpr int NBLK = NC * SPP;           // 1536 blocks
constexpr int NTHR = 512;                // 8 waves
constexpr int TROWS = RSTRIP + 6;        // 38 tile rows (±3 halo)
constexpr int LROW = W + 8;              // 520 words per LDS row (zero pads both sides)
constexpr int NF4 = TROWS * (W / 4);     // 4864 float4 slots to stage
constexpr float INV_K2 = 1.0f / 49.0f;
constexpr float INV_TOTAL = 1.0f / (32.0f * 3.0f * 512.0f * 512.0f);
}

// One row step for FOUR columns c0..c0+3 (c0 = 4k). rowp = &sm[r*LROW + 4k]:
//   A = words[4k..4k+3]   = cols c0-4..c0-1 (A.y..A.w = left halo)
//   B = words[4k+4..4k+7] = cols c0..c0+3   (centers)
//   C = words[4k+8..4k+11]= cols c0+4..c0+7 (right halo; C.w unused)
// P8/P4 compile-time ring phases -> all indices static (no scratch).
template <int P8, int P4, bool EMIT>
__device__ __forceinline__ void step4(const float* __restrict__ rowp,
                                      float (&hr)[8][4], float (&dr)[4][4],
                                      float (&vs)[4], float& acc)
{
    const float4 A = *(const float4*)(rowp);
    const float4 B = *(const float4*)(rowp + 4);
    const float4 C = *(const float4*)(rowp + 8);

    const float h0 = ((A.y + A.z) + (A.w + B.x)) + ((B.y + B.z) + B.w);
    const float h1 = h0 - A.y + C.x;
    const float h2 = h1 - A.z + C.y;
    const float h3 = h2 - A.w + C.z;

    constexpr int S  = P8 & 7;
    constexpr int So = (P8 + 1) & 7;   // h from 7 steps ago
    constexpr int Q  = P4 & 3;
    constexpr int Qo = (P4 + 1) & 3;   // d from 3 steps ago

    vs[0] += h0 - hr[So][0]; hr[S][0] = h0;
    vs[1] += h1 - hr[So][1]; hr[S][1] = h1;
    vs[2] += h2 - hr[So][2]; hr[S][2] = h2;
    vs[3] += h3 - hr[So][3]; hr[S][3] = h3;

    if (EMIT) {
        acc += fabsf(dr[Qo][0] - vs[0] * INV_K2)
             + fabsf(dr[Qo][1] - vs[1] * INV_K2)
             + fabsf(dr[Qo][2] - vs[2] * INV_K2)
             + fabsf(dr[Qo][3] - vs[3] * INV_K2);
    }

    dr[Q][0] = B.x; dr[Q][1] = B.y; dr[Q][2] = B.z; dr[Q][3] = B.w;
}

// min-waves=4 (for 512-thr block: 2 blocks/CU) -> VGPR cap 128, relaxed vs
// natural ~90. Forcing tighter (R3/R4) spills the ring arrays wholesale.
__global__ __launch_bounds__(NTHR, 4) void lcl_partial(
    const float4* __restrict__ pred4, const float4* __restrict__ targ4,
    float* __restrict__ partials)
{
    __shared__ float sm[TROWS * LROW + 8];   // 38x520 tile + 8-slot reduce tail

    const int t     = threadIdx.x;
    const int plane = blockIdx.x >> 4;            // / SPP
    const int y0    = (blockIdx.x & 15) * RSTRIP;
    const int base4 = plane * (H * (W / 4));

    // zero the side pads: words {1,2,3} and {516,517,518} of each row
    if (t < TROWS * 6) {
        const int r = t / 6;
        const int k = t - 6 * r;
        sm[r * LROW + (k < 3 ? 1 + k : 513 + k)] = 0.f;
    }

    // stage d = pred - target, float4-granular, 10 independent iterations (MLP)
#pragma unroll
    for (int it = 0; it < 10; ++it) {
        const int i = t + it * NTHR;
        if (it < 9 || i < NF4) {
            const int r  = i >> 7;                // / 128 float4s per row
            const int cw = i & 127;
            const int y  = y0 - 3 + r;
            float4 d4 = make_float4(0.f, 0.f, 0.f, 0.f);
            if ((unsigned)y < (unsigned)H) {
                const float4 a = pred4[base4 + y * (W / 4) + cw];
                const float4 b = targ4[base4 + y * (W / 4) + cw];
                d4 = make_float4(a.x - b.x, a.y - b.y, a.z - b.z, a.w - b.w);
            }
            *(float4*)&sm[r * LROW + 4 + 4 * cw] = d4;
        }
    }
    __syncthreads();   // the ONLY tile barrier

    // compute: thread = (group g, col-owner k). Group g covers tile rows
    // [8g, 8g+14): 6 halo/prologue steps + 8 emitting steps (output rows
    // y0+8g .. y0+8g+7). Cols c0 = 4k .. 4k+3.
    const int g = t >> 7;                  // 0..3
    const int k = t & 127;                 // 0..127

    float hr[8][4], dr[4][4], vs[4];
#pragma unroll
    for (int s = 0; s < 8; ++s) { hr[s][0]=0.f; hr[s][1]=0.f; hr[s][2]=0.f; hr[s][3]=0.f; }
#pragma unroll
    for (int s = 0; s < 4; ++s) { dr[s][0]=0.f; dr[s][1]=0.f; dr[s][2]=0.f; dr[s][3]=0.f; }
    vs[0]=0.f; vs[1]=0.f; vs[2]=0.f; vs[3]=0.f;
    float acc = 0.f;

    const float* p = &sm[(8 * g) * LROW + 4 * k];

    // prologue: group-local steps 0..5 (no emit)
    step4<0, 0, false>(p + 0 * LROW, hr, dr, vs, acc);
    step4<1, 1, false>(p + 1 * LROW, hr, dr, vs, acc);
    step4<2, 2, false>(p + 2 * LROW, hr, dr, vs, acc);
    step4<3, 3, false>(p + 3 * LROW, hr, dr, vs, acc);
    step4<4, 0, false>(p + 4 * LROW, hr, dr, vs, acc);
    step4<5, 1, false>(p + 5 * LROW, hr, dr, vs, acc);

    // steady: steps 6..13 (emit output rows y0+8g .. y0+8g+7)
    {
        const float* q = p + 6 * LROW;
        step4<6, 2, true>(q + 0 * LROW, hr, dr, vs, acc);
        step4<7, 3, true>(q + 1 * LROW, hr, dr, vs, acc);
        step4<0, 0, true>(q + 2 * LROW, hr, dr, vs, acc);
        step4<1, 1, true>(q + 3 * LROW, hr, dr, vs, acc);
        step4<2, 2, true>(q + 4 * LROW, hr, dr, vs, acc);
        step4<3, 3, true>(q + 5 * LROW, hr, dr, vs, acc);
        step4<4, 0, true>(q + 6 * LROW, hr, dr, vs, acc);
        step4<5, 1, true>(q + 7 * LROW, hr, dr, vs, acc);
    }

    // block reduce: wave shfl-reduce -> 8 partials in LDS tail -> thread 0
#pragma unroll
    for (int off = 32; off > 0; off >>= 1)
        acc += __shfl_down(acc, off, 64);
    float* wred = &sm[TROWS * LROW];
    if ((t & 63) == 0) wred[t >> 6] = acc;
    __syncthreads();
    if (t == 0) {
        float s = ((wred[0] + wred[1]) + (wred[2] + wred[3]))
                + ((wred[4] + wred[5]) + (wred[6] + wred[7]));
        partials[blockIdx.x] = s;
    }
}

__global__ __launch_bounds__(256) void lcl_reduce(const float* __restrict__ partials,
                                                  float* __restrict__ out)
{
    __shared__ float wred[4];
    const int tid = threadIdx.x;
    float s = 0.0f;
    for (int i = tid; i < NBLK; i += 256) s += partials[i];
#pragma unroll
    for (int off = 32; off > 0; off >>= 1)
        s += __shfl_down(s, off, 64);
    if ((tid & 63) == 0) wred[tid >> 6] = s;
    __syncthreads();
    if (tid == 0) out[0] = ((wred[0] + wred[1]) + (wred[2] + wred[3])) * INV_TOTAL;
}

extern "C" void kernel_launch(void* const* d_in, const int* in_sizes, int n_in,
                              void* d_out, int out_size, void* d_ws, size_t ws_size,
                              hipStream_t stream) {
    const float4* pred4 = (const float4*)d_in[0];
    const float4* targ4 = (const float4*)d_in[1];
    float* out      = (float*)d_out;
    float* partials = (float*)d_ws;   // NBLK floats = 6 KB

    lcl_partial<<<NBLK, NTHR, 0, stream>>>(pred4, targ4, partials);
    lcl_reduce<<<1, 256, 0, stream>>>(partials, out);
}